// Round 14
// baseline (65.015 us; speedup 1.0000x reference)
//
#include <hip/hip_runtime.h>
#include <hip/hip_bf16.h>
#include <math.h>

#define BATCH 256
#define DM    768
#define REPR  1024
#define FF    3072

typedef __attribute__((ext_vector_type(8))) short bf16x8;
typedef __attribute__((ext_vector_type(4))) float f32x4;

__device__ __forceinline__ unsigned bf16rne(float f){
  union{float f; unsigned u;} x; x.f = f;
  return (x.u + 0x7FFFu + ((x.u >> 16) & 1u)) >> 16;
}
__device__ __forceinline__ unsigned pk2(float lo, float hi){
  return bf16rne(lo) | (bf16rne(hi) << 16);
}

// ---------------------------------------------------------------------------
// K1 gemm_g1: G1 split-4 (r12-exact loop): P1[z] = im @ Wv2 K-slices, B
// direct from raw f32 Wv2, depth-1 prefetch (r13 lesson: depth-2 regresses).
// NEW: last-block fixup fusion. After writing its partial, each block does
// one threadfence + atomicAdd(cnt[tile]); the 4th arriver per tile
// (old%4==3 -- exactly one winner for ANY starting counter value, so no
// reset kernel and replay-safe) re-reads the 4 partials (L2-hot, 32KB) and
// writes xf/xbf in fixup_x's exact sum order -> bit-identical to r12.
// ---------------------------------------------------------------------------
__global__ __launch_bounds__(256)
void gemm_g1(const float* __restrict__ Wv2, const float* __restrict__ im,
             const float* __restrict__ bv2, float* __restrict__ P1,
             float* __restrict__ xf, ushort* __restrict__ xbf,
             unsigned* __restrict__ cnt)
{
  const int z = blockIdx.z, bx = blockIdx.x, by = blockIdx.y;
  const int tid = threadIdx.x;
  const int lane = tid & 63, wid = tid >> 6;
  const int wr = wid >> 1, wc = wid & 1;
  const int arow = by * 32 + wr * 16 + (lane & 15);
  const int colb = bx * 64 + wc * 32;
  const int kq8  = (lane >> 4) * 8;
  const int kb   = z * 256;              // 8 K-steps per slice

  const float* apf  = im + (size_t)arow * REPR + kb + kq8;
  const int c0 = colb + (lane & 15), c1 = c0 + 16;
  const float* wrow = Wv2 + (size_t)(kb + kq8) * DM;

  f32x4 acc0 = (f32x4)(0.0f), acc1 = (f32x4)(0.0f);
  float4 a0c = *(const float4*)apf, a1c = *(const float4*)(apf + 4);
  float b0c[8], b1c[8];
  #pragma unroll
  for (int j = 0; j < 8; ++j) {
    b0c[j] = wrow[(size_t)j * DM + c0];
    b1c[j] = wrow[(size_t)j * DM + c1];
  }

  for (int s = 0; s < 8; ++s) {
    float4 a0n, a1n; float b0n[8], b1n[8];
    const bool more = (s + 1) < 8;
    if (more) {                          // depth-1 prefetch
      const float* a2 = apf + (s + 1) * 32;
      a0n = *(const float4*)a2; a1n = *(const float4*)(a2 + 4);
      const float* w2r = wrow + (size_t)(s + 1) * 32 * DM;
      #pragma unroll
      for (int j = 0; j < 8; ++j) {
        b0n[j] = w2r[(size_t)j * DM + c0];
        b1n[j] = w2r[(size_t)j * DM + c1];
      }
    }
    union U { unsigned u[4]; bf16x8 v; } afr, bfr0, bfr1;
    afr.u[0] = pk2(a0c.x, a0c.y); afr.u[1] = pk2(a0c.z, a0c.w);
    afr.u[2] = pk2(a1c.x, a1c.y); afr.u[3] = pk2(a1c.z, a1c.w);
    #pragma unroll
    for (int j = 0; j < 4; ++j) {
      bfr0.u[j] = pk2(b0c[2*j], b0c[2*j+1]);
      bfr1.u[j] = pk2(b1c[2*j], b1c[2*j+1]);
    }
    acc0 = __builtin_amdgcn_mfma_f32_16x16x32_bf16(afr.v, bfr0.v, acc0, 0, 0, 0);
    acc1 = __builtin_amdgcn_mfma_f32_16x16x32_bf16(afr.v, bfr1.v, acc1, 0, 0, 0);
    if (more) {
      a0c = a0n; a1c = a1n;
      #pragma unroll
      for (int j = 0; j < 8; ++j) { b0c[j] = b0n[j]; b1c[j] = b1n[j]; }
    }
  }

  const int crow = by * 32 + wr * 16 + (lane >> 4) * 4;
  float* dst = P1 + (size_t)z * BATCH * DM;
  #pragma unroll
  for (int nf = 0; nf < 2; ++nf) {
    const int c = colb + nf * 16 + (lane & 15);
    const f32x4 a = nf ? acc1 : acc0;
    #pragma unroll
    for (int r = 0; r < 4; ++r)
      dst[(size_t)(crow + r) * DM + c] = a[r];
  }

  // ---- last-block fixup for this (bx,by) tile ----
  __syncthreads();                       // all partial stores issued
  __shared__ unsigned winner;
  if (tid == 0) {
    __threadfence();                     // release: partials device-visible
    unsigned old = atomicAdd(&cnt[by * 12 + bx], 1u);
    winner = ((old & 3u) == 3u) ? 1u : 0u;
  }
  __syncthreads();
  if (winner) {
    __threadfence();                     // acquire: no stale reads
    // tile = rows [by*32,+32) x cols [bx*64,+64); 2048 els, 8 per thread
    const int row = by * 32 + (tid >> 3);
    const int col = bx * 64 + (tid & 7) * 8;
    const size_t e = (size_t)row * DM + col;
    #pragma unroll
    for (int h = 0; h < 2; ++h) {        // two float4 chunks
      const size_t eh = e + h * 4;
      float4 s = *(const float4*)(P1 + eh);
      #pragma unroll
      for (int zz = 1; zz < 4; ++zz) {
        float4 v = *(const float4*)(P1 + (size_t)zz * BATCH * DM + eh);
        s.x += v.x; s.y += v.y; s.z += v.z; s.w += v.w;
      }
      float4 bb = *(const float4*)(bv2 + col + h * 4);
      s.x += bb.x; s.y += bb.y; s.z += bb.z; s.w += bb.w;
      *(float4*)(xf + eh) = s;
      uint2 o = { pk2(s.x, s.y), pk2(s.z, s.w) };
      *(uint2*)(xbf + eh) = o;
    }
  }
}

// ---------------------------------------------------------------------------
// K2 gemm_g2 (r12-exact): A = xbf bf16; B direct from f32 W1 [DM][FF].
// Grid (48,8), 24 K-steps, depth-1 prefetch. Epi: +b1, exact gelu -> bf16.
// ---------------------------------------------------------------------------
__global__ __launch_bounds__(256)
void gemm_g2(const ushort* __restrict__ xbf, const float* __restrict__ W1,
             const float* __restrict__ b1, ushort* __restrict__ tbf)
{
  int id = blockIdx.y * 48 + blockIdx.x;
  id = (id & 7) * 48 + (id >> 3);        // XCD swizzle (384 % 8 == 0)
  const int bx = id / 8, by = id % 8;

  const int lane = threadIdx.x & 63, wid = threadIdx.x >> 6;
  const int wr = wid >> 1, wc = wid & 1;
  const int arow = by * 32 + wr * 16 + (lane & 15);
  const int colb = bx * 64 + wc * 32;
  const int kq = (lane >> 4) * 8;

  const ushort* ap = xbf + (size_t)arow * DM + kq;
  const int c0 = colb + (lane & 15), c1 = c0 + 16;
  const float* wrow = W1 + (size_t)kq * FF;

  f32x4 acc0 = (f32x4)(0.0f), acc1 = (f32x4)(0.0f);
  union U { uint4 q; bf16x8 v; };
  U a_c;
  a_c.q = *(const uint4*)ap;
  float b0c[8], b1c[8];
  #pragma unroll
  for (int j = 0; j < 8; ++j) {
    b0c[j] = wrow[(size_t)j * FF + c0];
    b1c[j] = wrow[(size_t)j * FF + c1];
  }

  for (int t = 0; t < 24; ++t) {
    U a_n; float b0n[8], b1n[8];
    const bool more = (t + 1) < 24;
    if (more) {                          // issue next-step loads before MFMA
      a_n.q = *(const uint4*)(ap + (t + 1) * 32);
      const float* w2r = wrow + (size_t)(t + 1) * 32 * FF;
      #pragma unroll
      for (int j = 0; j < 8; ++j) {
        b0n[j] = w2r[(size_t)j * FF + c0];
        b1n[j] = w2r[(size_t)j * FF + c1];
      }
    }
    union V { unsigned u[4]; bf16x8 v; } bfr0, bfr1;
    #pragma unroll
    for (int j = 0; j < 4; ++j) {
      bfr0.u[j] = pk2(b0c[2*j], b0c[2*j+1]);
      bfr1.u[j] = pk2(b1c[2*j], b1c[2*j+1]);
    }
    acc0 = __builtin_amdgcn_mfma_f32_16x16x32_bf16(a_c.v, bfr0.v, acc0, 0, 0, 0);
    acc1 = __builtin_amdgcn_mfma_f32_16x16x32_bf16(a_c.v, bfr1.v, acc1, 0, 0, 0);
    if (more) {
      a_c = a_n;
      #pragma unroll
      for (int j = 0; j < 8; ++j) { b0c[j] = b0n[j]; b1c[j] = b1n[j]; }
    }
  }

  const int crow = by * 32 + wr * 16 + (lane >> 4) * 4;
  #pragma unroll
  for (int nf = 0; nf < 2; ++nf) {
    const int c = colb + nf * 16 + (lane & 15);
    const f32x4 a = nf ? acc1 : acc0;
    #pragma unroll
    for (int r = 0; r < 4; ++r) {
      float v = a[r] + b1[c];
      v = 0.5f * v * (1.0f + erff(v * 0.70710678118654752f));
      tbf[(size_t)(crow + r) * FF + c] = (ushort)bf16rne(v);
    }
  }
}

// ---------------------------------------------------------------------------
// K3 gemm_g3 (r12-exact): A = tbf bf16; B direct from f32 W2 [FF][DM].
// Split-8, grid (12,8,8), 12 K-steps, depth-1. Epi: f32 partial -> P3[z].
// ---------------------------------------------------------------------------
__global__ __launch_bounds__(256)
void gemm_g3(const ushort* __restrict__ tbf, const float* __restrict__ W2,
             float* __restrict__ P3)
{
  int id = blockIdx.y * 12 + blockIdx.x;
  id = (id & 7) * 12 + (id >> 3);        // XCD swizzle (96 % 8 == 0)
  const int bx = id / 8, by = id % 8;

  const int lane = threadIdx.x & 63, wid = threadIdx.x >> 6;
  const int wr = wid >> 1, wc = wid & 1;
  const int arow = by * 32 + wr * 16 + (lane & 15);
  const int colb = bx * 64 + wc * 32;
  const int kq = (lane >> 4) * 8;
  const int kb = blockIdx.z * 384;

  const ushort* ap = tbf + (size_t)arow * FF + kb + kq;
  const int c0 = colb + (lane & 15), c1 = c0 + 16;
  const float* wrow = W2 + (size_t)(kb + kq) * DM;

  f32x4 acc0 = (f32x4)(0.0f), acc1 = (f32x4)(0.0f);
  union U { uint4 q; bf16x8 v; };
  U a_c;
  a_c.q = *(const uint4*)ap;
  float b0c[8], b1c[8];
  #pragma unroll
  for (int j = 0; j < 8; ++j) {
    b0c[j] = wrow[(size_t)j * DM + c0];
    b1c[j] = wrow[(size_t)j * DM + c1];
  }

  for (int t = 0; t < 12; ++t) {
    U a_n; float b0n[8], b1n[8];
    const bool more = (t + 1) < 12;
    if (more) {                          // issue next-step loads before MFMA
      a_n.q = *(const uint4*)(ap + (t + 1) * 32);
      const float* w2r = wrow + (size_t)(t + 1) * 32 * DM;
      #pragma unroll
      for (int j = 0; j < 8; ++j) {
        b0n[j] = w2r[(size_t)j * DM + c0];
        b1n[j] = w2r[(size_t)j * DM + c1];
      }
    }
    union V { unsigned u[4]; bf16x8 v; } bfr0, bfr1;
    #pragma unroll
    for (int j = 0; j < 4; ++j) {
      bfr0.u[j] = pk2(b0c[2*j], b0c[2*j+1]);
      bfr1.u[j] = pk2(b1c[2*j], b1c[2*j+1]);
    }
    acc0 = __builtin_amdgcn_mfma_f32_16x16x32_bf16(a_c.v, bfr0.v, acc0, 0, 0, 0);
    acc1 = __builtin_amdgcn_mfma_f32_16x16x32_bf16(a_c.v, bfr1.v, acc1, 0, 0, 0);
    if (more) {
      a_c = a_n;
      #pragma unroll
      for (int j = 0; j < 8; ++j) { b0c[j] = b0n[j]; b1c[j] = b1n[j]; }
    }
  }

  const int crow = by * 32 + wr * 16 + (lane >> 4) * 4;
  float* dst = P3 + (size_t)blockIdx.z * BATCH * DM;
  #pragma unroll
  for (int nf = 0; nf < 2; ++nf) {
    const int c = colb + nf * 16 + (lane & 15);
    const f32x4 a = nf ? acc1 : acc0;
    #pragma unroll
    for (int r = 0; r < 4; ++r)
      dst[(size_t)(crow + r) * DM + c] = a[r];
  }
}

// ---------------------------------------------------------------------------
// K4 ln_final (r12-exact): y = xf + sum_{z<8} P3[z] + b2, LayerNorm -> out.
// ---------------------------------------------------------------------------
__global__ __launch_bounds__(256)
void ln_final(const float* __restrict__ P3, const float* __restrict__ xf,
              const float* __restrict__ b2, const float* __restrict__ g,
              const float* __restrict__ be, float* __restrict__ out)
{
  const int row = blockIdx.x, tid = threadIdx.x;
  const int lane = tid & 63, wave = tid >> 6;

  float v[3];
  #pragma unroll
  for (int i = 0; i < 3; ++i) {
    const int c = tid + i * 256;
    float s = xf[(size_t)row * DM + c] + b2[c];
    #pragma unroll
    for (int z = 0; z < 8; ++z) s += P3[((size_t)z * BATCH + row) * DM + c];
    v[i] = s;
  }

  __shared__ float red[4];
  float s = v[0] + v[1] + v[2];
  #pragma unroll
  for (int o = 32; o > 0; o >>= 1) s += __shfl_down(s, o);
  if (lane == 0) red[wave] = s;
  __syncthreads();
  const float mu = (red[0] + red[1] + red[2] + red[3]) * (1.0f / 768.0f);
  __syncthreads();
  const float d0 = v[0] - mu, d1 = v[1] - mu, d2 = v[2] - mu;
  float q = d0*d0 + d1*d1 + d2*d2;
  #pragma unroll
  for (int o = 32; o > 0; o >>= 1) q += __shfl_down(q, o);
  if (lane == 0) red[wave] = q;
  __syncthreads();
  const float var = (red[0] + red[1] + red[2] + red[3]) * (1.0f / 768.0f);
  const float inv = rsqrtf(var + 1e-12f);

  float* o = out + (size_t)row * DM;
  o[tid      ] = d0 * inv * g[tid      ] + be[tid      ];
  o[tid + 256] = d1 * inv * g[tid + 256] + be[tid + 256];
  o[tid + 512] = d2 * inv * g[tid + 512] + be[tid + 512];
}

// ---------------------------------------------------------------------------
// 4 kernels: G1(+last-block fixup) -> G2 -> G3 (split-8) -> LN.
// Bit-identical output to r12. ws ~11.2 MB + 384B counters.
// ---------------------------------------------------------------------------
extern "C" void kernel_launch(void* const* d_in, const int* in_sizes, int n_in,
                              void* d_out, int out_size, void* d_ws, size_t ws_size,
                              hipStream_t stream)
{
  const float* im  = (const float*)d_in[0];
  const float* Wv2 = (const float*)d_in[12];
  const float* bv2 = (const float*)d_in[13];
  const float* W1  = (const float*)d_in[14];
  const float* b1  = (const float*)d_in[15];
  const float* W2  = (const float*)d_in[16];
  const float* b2  = (const float*)d_in[17];
  const float* g   = (const float*)d_in[18];
  const float* be  = (const float*)d_in[19];
  float* out = (float*)d_out;

  char* w = (char*)d_ws;
  ushort*   xbf = (ushort*)(w);              // 256*768*2   = 393216
  ushort*   tbf = (ushort*)(w + 393216);     // 256*3072*2  = 1572864
  float*    xf  = (float*) (w + 1966080);    // 256*768*4   = 786432
  float*    P1  = (float*) (w + 2752512);    // 4*256*768*4 = 3145728
  float*    P3  = (float*) (w + 5898240);    // 8*256*768*4 = 6291456
  unsigned* cnt = (unsigned*)(w + 12189696); // 96*4        = 384 -> ~11.2MB

  // K1: P1[z] = im @ Wv2 slices; 4th arriver per tile sums + bv2 -> xf,xbf
  gemm_g1<<<dim3(12, 8, 4), 256, 0, stream>>>(Wv2, im, bv2, P1, xf, xbf, cnt);
  // K2: tbf = bf16(gelu(x @ W1 + b1))   (direct f32 B)
  gemm_g2<<<dim3(48, 8, 1), 256, 0, stream>>>(xbf, W1, b1, tbf);
  // K3: P3[z] = (t @ W2) K-slices       (direct f32 B, split-8)
  gemm_g3<<<dim3(12, 8, 8), 256, 0, stream>>>(tbf, W2, P3);
  // K4: LN(xf + sum P3 + b2) -> out
  ln_final<<<BATCH, 256, 0, stream>>>(P3, xf, b2, g, be, out);
}

// Round 15
// 49.377 us; speedup vs baseline: 1.3167x; 1.3167x over previous
//
#include <hip/hip_runtime.h>
#include <hip/hip_bf16.h>
#include <math.h>

#define BATCH 256
#define DM    768
#define REPR  1024
#define FF    3072

typedef __attribute__((ext_vector_type(8))) short bf16x8;
typedef __attribute__((ext_vector_type(4))) float f32x4;

__device__ __forceinline__ unsigned bf16rne(float f){
  union{float f; unsigned u;} x; x.f = f;
  return (x.u + 0x7FFFu + ((x.u >> 16) & 1u)) >> 16;
}
__device__ __forceinline__ unsigned pk2(float lo, float hi){
  return bf16rne(lo) | (bf16rne(hi) << 16);
}

// ---------------------------------------------------------------------------
// K1 gemm_g1 (r12-exact): G1 split-4: P1[z] = im @ Wv2 K-slices, B direct
// from raw f32 Wv2, depth-1 prefetch. Grid (12,8,4).
// ---------------------------------------------------------------------------
__global__ __launch_bounds__(256)
void gemm_g1(const float* __restrict__ Wv2, const float* __restrict__ im,
             float* __restrict__ P1)
{
  const int z = blockIdx.z, bx = blockIdx.x, by = blockIdx.y;
  const int tid = threadIdx.x;
  const int lane = tid & 63, wid = tid >> 6;
  const int wr = wid >> 1, wc = wid & 1;
  const int arow = by * 32 + wr * 16 + (lane & 15);
  const int colb = bx * 64 + wc * 32;
  const int kq8  = (lane >> 4) * 8;
  const int kb   = z * 256;              // 8 K-steps per slice

  const float* apf  = im + (size_t)arow * REPR + kb + kq8;
  const int c0 = colb + (lane & 15), c1 = c0 + 16;
  const float* wrow = Wv2 + (size_t)(kb + kq8) * DM;

  f32x4 acc0 = (f32x4)(0.0f), acc1 = (f32x4)(0.0f);
  float4 a0c = *(const float4*)apf, a1c = *(const float4*)(apf + 4);
  float b0c[8], b1c[8];
  #pragma unroll
  for (int j = 0; j < 8; ++j) {
    b0c[j] = wrow[(size_t)j * DM + c0];
    b1c[j] = wrow[(size_t)j * DM + c1];
  }

  for (int s = 0; s < 8; ++s) {
    float4 a0n, a1n; float b0n[8], b1n[8];
    const bool more = (s + 1) < 8;
    if (more) {                          // depth-1 prefetch
      const float* a2 = apf + (s + 1) * 32;
      a0n = *(const float4*)a2; a1n = *(const float4*)(a2 + 4);
      const float* w2r = wrow + (size_t)(s + 1) * 32 * DM;
      #pragma unroll
      for (int j = 0; j < 8; ++j) {
        b0n[j] = w2r[(size_t)j * DM + c0];
        b1n[j] = w2r[(size_t)j * DM + c1];
      }
    }
    union U { unsigned u[4]; bf16x8 v; } afr, bfr0, bfr1;
    afr.u[0] = pk2(a0c.x, a0c.y); afr.u[1] = pk2(a0c.z, a0c.w);
    afr.u[2] = pk2(a1c.x, a1c.y); afr.u[3] = pk2(a1c.z, a1c.w);
    #pragma unroll
    for (int j = 0; j < 4; ++j) {
      bfr0.u[j] = pk2(b0c[2*j], b0c[2*j+1]);
      bfr1.u[j] = pk2(b1c[2*j], b1c[2*j+1]);
    }
    acc0 = __builtin_amdgcn_mfma_f32_16x16x32_bf16(afr.v, bfr0.v, acc0, 0, 0, 0);
    acc1 = __builtin_amdgcn_mfma_f32_16x16x32_bf16(afr.v, bfr1.v, acc1, 0, 0, 0);
    if (more) {
      a0c = a0n; a1c = a1n;
      #pragma unroll
      for (int j = 0; j < 8; ++j) { b0c[j] = b0n[j]; b1c[j] = b1n[j]; }
    }
  }

  const int crow = by * 32 + wr * 16 + (lane >> 4) * 4;
  float* dst = P1 + (size_t)z * BATCH * DM;
  #pragma unroll
  for (int nf = 0; nf < 2; ++nf) {
    const int c = colb + nf * 16 + (lane & 15);
    const f32x4 a = nf ? acc1 : acc0;
    #pragma unroll
    for (int r = 0; r < 4; ++r)
      dst[(size_t)(crow + r) * DM + c] = a[r];
  }
}

// ---------------------------------------------------------------------------
// K2 fixup_x (r12-exact): x = sum_z P1[z] + bv2 -> xf (f32) + xbf (bf16).
// ---------------------------------------------------------------------------
__global__ __launch_bounds__(256)
void fixup_x(const float* __restrict__ P1, const float* __restrict__ bv2,
             float* __restrict__ xf, ushort* __restrict__ xbf)
{
  const int e = (blockIdx.x * 256 + threadIdx.x) * 4;
  const int c = e % DM;
  float4 s = *(const float4*)(P1 + e);
  #pragma unroll
  for (int z = 1; z < 4; ++z) {
    float4 v = *(const float4*)(P1 + (size_t)z * BATCH * DM + e);
    s.x += v.x; s.y += v.y; s.z += v.z; s.w += v.w;
  }
  float4 bb = *(const float4*)(bv2 + c);
  s.x += bb.x; s.y += bb.y; s.z += bb.z; s.w += bb.w;
  *(float4*)(xf + e) = s;
  uint2 o = { pk2(s.x, s.y), pk2(s.z, s.w) };
  *(uint2*)(xbf + e) = o;
}

// ---------------------------------------------------------------------------
// K3 gemm_g2: NARROW 32x32 tile (was 32x64). 4 waves 2x2 of 16x16; 1 MFMA +
// 48 B/lane/step (was 2 MFMA + 80B). Grid (96,8) = 768 blocks = 3 waves/SIMD
// (2x the TLP -- the latency-hiding lever). Per-fragment math identical to
// r12 -> bit-identical output. A = xbf bf16; B direct f32 W1; depth-1.
// ---------------------------------------------------------------------------
__global__ __launch_bounds__(256)
void gemm_g2(const ushort* __restrict__ xbf, const float* __restrict__ W1,
             const float* __restrict__ b1, ushort* __restrict__ tbf)
{
  int id = blockIdx.y * 96 + blockIdx.x;
  id = (id & 7) * 96 + (id >> 3);        // XCD swizzle (768 % 8 == 0)
  const int bx = id / 8, by = id % 8;

  const int lane = threadIdx.x & 63, wid = threadIdx.x >> 6;
  const int wr = wid >> 1, wc = wid & 1;
  const int arow = by * 32 + wr * 16 + (lane & 15);
  const int c0   = bx * 32 + wc * 16 + (lane & 15);
  const int kq = (lane >> 4) * 8;

  const ushort* ap = xbf + (size_t)arow * DM + kq;
  const float* wrow = W1 + (size_t)kq * FF;

  f32x4 acc0 = (f32x4)(0.0f);
  union U { uint4 q; bf16x8 v; };
  U a_c;
  a_c.q = *(const uint4*)ap;
  float b0c[8];
  #pragma unroll
  for (int j = 0; j < 8; ++j)
    b0c[j] = wrow[(size_t)j * FF + c0];

  for (int t = 0; t < 24; ++t) {
    U a_n; float b0n[8];
    const bool more = (t + 1) < 24;
    if (more) {                          // issue next-step loads before MFMA
      a_n.q = *(const uint4*)(ap + (t + 1) * 32);
      const float* w2r = wrow + (size_t)(t + 1) * 32 * FF;
      #pragma unroll
      for (int j = 0; j < 8; ++j)
        b0n[j] = w2r[(size_t)j * FF + c0];
    }
    union V { unsigned u[4]; bf16x8 v; } bfr0;
    #pragma unroll
    for (int j = 0; j < 4; ++j)
      bfr0.u[j] = pk2(b0c[2*j], b0c[2*j+1]);
    acc0 = __builtin_amdgcn_mfma_f32_16x16x32_bf16(a_c.v, bfr0.v, acc0, 0, 0, 0);
    if (more) {
      a_c = a_n;
      #pragma unroll
      for (int j = 0; j < 8; ++j) b0c[j] = b0n[j];
    }
  }

  const int crow = by * 32 + wr * 16 + (lane >> 4) * 4;
  #pragma unroll
  for (int r = 0; r < 4; ++r) {
    float v = acc0[r] + b1[c0];
    v = 0.5f * v * (1.0f + erff(v * 0.70710678118654752f));
    tbf[(size_t)(crow + r) * FF + c0] = (ushort)bf16rne(v);
  }
}

// ---------------------------------------------------------------------------
// K4 gemm_g3: NARROW 32x32 tile, split-8. Grid (24,8,8) = 1536 blocks =
// 6 waves/SIMD. A = tbf bf16; B direct f32 W2 [FF][DM]; 12 K-steps, depth-1.
// Epi: f32 partial -> P3[z]. Bit-identical per-fragment math to r12.
// ---------------------------------------------------------------------------
__global__ __launch_bounds__(256)
void gemm_g3(const ushort* __restrict__ tbf, const float* __restrict__ W2,
             float* __restrict__ P3)
{
  int id = blockIdx.y * 24 + blockIdx.x;
  id = (id & 7) * 24 + (id >> 3);        // XCD swizzle (192 % 8 == 0)
  const int bx = id / 8, by = id % 8;

  const int lane = threadIdx.x & 63, wid = threadIdx.x >> 6;
  const int wr = wid >> 1, wc = wid & 1;
  const int arow = by * 32 + wr * 16 + (lane & 15);
  const int c0   = bx * 32 + wc * 16 + (lane & 15);
  const int kq = (lane >> 4) * 8;
  const int kb = blockIdx.z * 384;

  const ushort* ap = tbf + (size_t)arow * FF + kb + kq;
  const float* wrow = W2 + (size_t)(kb + kq) * DM;

  f32x4 acc0 = (f32x4)(0.0f);
  union U { uint4 q; bf16x8 v; };
  U a_c;
  a_c.q = *(const uint4*)ap;
  float b0c[8];
  #pragma unroll
  for (int j = 0; j < 8; ++j)
    b0c[j] = wrow[(size_t)j * DM + c0];

  for (int t = 0; t < 12; ++t) {
    U a_n; float b0n[8];
    const bool more = (t + 1) < 12;
    if (more) {                          // issue next-step loads before MFMA
      a_n.q = *(const uint4*)(ap + (t + 1) * 32);
      const float* w2r = wrow + (size_t)(t + 1) * 32 * DM;
      #pragma unroll
      for (int j = 0; j < 8; ++j)
        b0n[j] = w2r[(size_t)j * DM + c0];
    }
    union V { unsigned u[4]; bf16x8 v; } bfr0;
    #pragma unroll
    for (int j = 0; j < 4; ++j)
      bfr0.u[j] = pk2(b0c[2*j], b0c[2*j+1]);
    acc0 = __builtin_amdgcn_mfma_f32_16x16x32_bf16(a_c.v, bfr0.v, acc0, 0, 0, 0);
    if (more) {
      a_c = a_n;
      #pragma unroll
      for (int j = 0; j < 8; ++j) b0c[j] = b0n[j];
    }
  }

  const int crow = by * 32 + wr * 16 + (lane >> 4) * 4;
  float* dst = P3 + (size_t)blockIdx.z * BATCH * DM;
  #pragma unroll
  for (int r = 0; r < 4; ++r)
    dst[(size_t)(crow + r) * DM + c0] = acc0[r];
}

// ---------------------------------------------------------------------------
// K5 ln_final (r12-exact): y = xf + sum_{z<8} P3[z] + b2, LayerNorm -> out.
// ---------------------------------------------------------------------------
__global__ __launch_bounds__(256)
void ln_final(const float* __restrict__ P3, const float* __restrict__ xf,
              const float* __restrict__ b2, const float* __restrict__ g,
              const float* __restrict__ be, float* __restrict__ out)
{
  const int row = blockIdx.x, tid = threadIdx.x;
  const int lane = tid & 63, wave = tid >> 6;

  float v[3];
  #pragma unroll
  for (int i = 0; i < 3; ++i) {
    const int c = tid + i * 256;
    float s = xf[(size_t)row * DM + c] + b2[c];
    #pragma unroll
    for (int z = 0; z < 8; ++z) s += P3[((size_t)z * BATCH + row) * DM + c];
    v[i] = s;
  }

  __shared__ float red[4];
  float s = v[0] + v[1] + v[2];
  #pragma unroll
  for (int o = 32; o > 0; o >>= 1) s += __shfl_down(s, o);
  if (lane == 0) red[wave] = s;
  __syncthreads();
  const float mu = (red[0] + red[1] + red[2] + red[3]) * (1.0f / 768.0f);
  __syncthreads();
  const float d0 = v[0] - mu, d1 = v[1] - mu, d2 = v[2] - mu;
  float q = d0*d0 + d1*d1 + d2*d2;
  #pragma unroll
  for (int o = 32; o > 0; o >>= 1) q += __shfl_down(q, o);
  if (lane == 0) red[wave] = q;
  __syncthreads();
  const float var = (red[0] + red[1] + red[2] + red[3]) * (1.0f / 768.0f);
  const float inv = rsqrtf(var + 1e-12f);

  float* o = out + (size_t)row * DM;
  o[tid      ] = d0 * inv * g[tid      ] + be[tid      ];
  o[tid + 256] = d1 * inv * g[tid + 256] + be[tid + 256];
  o[tid + 512] = d2 * inv * g[tid + 512] + be[tid + 512];
}

// ---------------------------------------------------------------------------
// 5 kernels (r12 structure; G2/G3 narrowed to 32-col tiles for 2x TLP):
// G1 -> fixup -> G2 -> G3 -> LN. Bit-identical output to r12. ws ~11.2 MB.
// ---------------------------------------------------------------------------
extern "C" void kernel_launch(void* const* d_in, const int* in_sizes, int n_in,
                              void* d_out, int out_size, void* d_ws, size_t ws_size,
                              hipStream_t stream)
{
  const float* im  = (const float*)d_in[0];
  const float* Wv2 = (const float*)d_in[12];
  const float* bv2 = (const float*)d_in[13];
  const float* W1  = (const float*)d_in[14];
  const float* b1  = (const float*)d_in[15];
  const float* W2  = (const float*)d_in[16];
  const float* b2  = (const float*)d_in[17];
  const float* g   = (const float*)d_in[18];
  const float* be  = (const float*)d_in[19];
  float* out = (float*)d_out;

  char* w = (char*)d_ws;
  ushort* xbf = (ushort*)(w);                // 256*768*2   = 393216
  ushort* tbf = (ushort*)(w + 393216);       // 256*3072*2  = 1572864
  float*  xf  = (float*) (w + 1966080);      // 256*768*4   = 786432
  float*  P1  = (float*) (w + 2752512);      // 4*256*768*4 = 3145728
  float*  P3  = (float*) (w + 5898240);      // 8*256*768*4 = 6291456 -> 11.2MB

  // K1: P1[z] = im @ Wv2 slices (direct f32 B, split-4)
  gemm_g1<<<dim3(12, 8, 4), 256, 0, stream>>>(Wv2, im, P1);
  // K2: x = sum P1 + bv2 -> xf, xbf
  fixup_x<<<192, 256, 0, stream>>>(P1, bv2, xf, xbf);
  // K3: tbf = bf16(gelu(x @ W1 + b1))   (32-wide tiles, 768 blocks)
  gemm_g2<<<dim3(96, 8, 1), 256, 0, stream>>>(xbf, W1, b1, tbf);
  // K4: P3[z] = (t @ W2) K-slices       (32-wide tiles, split-8, 1536 blocks)
  gemm_g3<<<dim3(24, 8, 8), 256, 0, stream>>>(tbf, W2, P3);
  // K5: LN(xf + sum P3 + b2) -> out
  ln_final<<<BATCH, 256, 0, stream>>>(P3, xf, b2, g, be, out);
}

// Round 16
// 45.914 us; speedup vs baseline: 1.4160x; 1.0754x over previous
//
#include <hip/hip_runtime.h>
#include <hip/hip_bf16.h>
#include <math.h>

#define BATCH 256
#define DM    768
#define REPR  1024
#define FF    3072

typedef __attribute__((ext_vector_type(8))) short bf16x8;
typedef __attribute__((ext_vector_type(4))) float f32x4;

__device__ __forceinline__ unsigned bf16rne(float f){
  union{float f; unsigned u;} x; x.f = f;
  return (x.u + 0x7FFFu + ((x.u >> 16) & 1u)) >> 16;
}
__device__ __forceinline__ unsigned pk2(float lo, float hi){
  return bf16rne(lo) | (bf16rne(hi) << 16);
}

// ---------------------------------------------------------------------------
// K1 gemm_g1: G1 split-8 (was split-4): P1[z] = im @ Wv2 K-slices, B direct
// from raw f32 Wv2, depth-1 prefetch. Grid (12,8,8), 4 K-steps per block --
// half the serial chain of r12 (split-K as latency amortization, r9 lesson).
// ---------------------------------------------------------------------------
__global__ __launch_bounds__(256)
void gemm_g1(const float* __restrict__ Wv2, const float* __restrict__ im,
             float* __restrict__ P1)
{
  const int z = blockIdx.z, bx = blockIdx.x, by = blockIdx.y;
  const int tid = threadIdx.x;
  const int lane = tid & 63, wid = tid >> 6;
  const int wr = wid >> 1, wc = wid & 1;
  const int arow = by * 32 + wr * 16 + (lane & 15);
  const int colb = bx * 64 + wc * 32;
  const int kq8  = (lane >> 4) * 8;
  const int kb   = z * 128;              // 4 K-steps per slice

  const float* apf  = im + (size_t)arow * REPR + kb + kq8;
  const int c0 = colb + (lane & 15), c1 = c0 + 16;
  const float* wrow = Wv2 + (size_t)(kb + kq8) * DM;

  f32x4 acc0 = (f32x4)(0.0f), acc1 = (f32x4)(0.0f);
  float4 a0c = *(const float4*)apf, a1c = *(const float4*)(apf + 4);
  float b0c[8], b1c[8];
  #pragma unroll
  for (int j = 0; j < 8; ++j) {
    b0c[j] = wrow[(size_t)j * DM + c0];
    b1c[j] = wrow[(size_t)j * DM + c1];
  }

  for (int s = 0; s < 4; ++s) {
    float4 a0n, a1n; float b0n[8], b1n[8];
    const bool more = (s + 1) < 4;
    if (more) {                          // depth-1 prefetch
      const float* a2 = apf + (s + 1) * 32;
      a0n = *(const float4*)a2; a1n = *(const float4*)(a2 + 4);
      const float* w2r = wrow + (size_t)(s + 1) * 32 * DM;
      #pragma unroll
      for (int j = 0; j < 8; ++j) {
        b0n[j] = w2r[(size_t)j * DM + c0];
        b1n[j] = w2r[(size_t)j * DM + c1];
      }
    }
    union U { unsigned u[4]; bf16x8 v; } afr, bfr0, bfr1;
    afr.u[0] = pk2(a0c.x, a0c.y); afr.u[1] = pk2(a0c.z, a0c.w);
    afr.u[2] = pk2(a1c.x, a1c.y); afr.u[3] = pk2(a1c.z, a1c.w);
    #pragma unroll
    for (int j = 0; j < 4; ++j) {
      bfr0.u[j] = pk2(b0c[2*j], b0c[2*j+1]);
      bfr1.u[j] = pk2(b1c[2*j], b1c[2*j+1]);
    }
    acc0 = __builtin_amdgcn_mfma_f32_16x16x32_bf16(afr.v, bfr0.v, acc0, 0, 0, 0);
    acc1 = __builtin_amdgcn_mfma_f32_16x16x32_bf16(afr.v, bfr1.v, acc1, 0, 0, 0);
    if (more) {
      a0c = a0n; a1c = a1n;
      #pragma unroll
      for (int j = 0; j < 8; ++j) { b0c[j] = b0n[j]; b1c[j] = b1n[j]; }
    }
  }

  const int crow = by * 32 + wr * 16 + (lane >> 4) * 4;
  float* dst = P1 + (size_t)z * BATCH * DM;
  #pragma unroll
  for (int nf = 0; nf < 2; ++nf) {
    const int c = colb + nf * 16 + (lane & 15);
    const f32x4 a = nf ? acc1 : acc0;
    #pragma unroll
    for (int r = 0; r < 4; ++r)
      dst[(size_t)(crow + r) * DM + c] = a[r];
  }
}

// ---------------------------------------------------------------------------
// K2 fixup_x: x = sum_{z<8} P1[z] + bv2 -> xf (f32) + xbf (bf16).
// ---------------------------------------------------------------------------
__global__ __launch_bounds__(256)
void fixup_x(const float* __restrict__ P1, const float* __restrict__ bv2,
             float* __restrict__ xf, ushort* __restrict__ xbf)
{
  const int e = (blockIdx.x * 256 + threadIdx.x) * 4;
  const int c = e % DM;
  float4 s = *(const float4*)(P1 + e);
  #pragma unroll
  for (int z = 1; z < 8; ++z) {
    float4 v = *(const float4*)(P1 + (size_t)z * BATCH * DM + e);
    s.x += v.x; s.y += v.y; s.z += v.z; s.w += v.w;
  }
  float4 bb = *(const float4*)(bv2 + c);
  s.x += bb.x; s.y += bb.y; s.z += bb.z; s.w += bb.w;
  *(float4*)(xf + e) = s;
  uint2 o = { pk2(s.x, s.y), pk2(s.z, s.w) };
  *(uint2*)(xbf + e) = o;
}

// ---------------------------------------------------------------------------
// K3 gemm_g2 (r12-exact): A = xbf bf16; B direct from f32 W1 [DM][FF].
// Grid (48,8), 24 K-steps, depth-1 prefetch. Epi: +b1, exact gelu -> bf16.
// ---------------------------------------------------------------------------
__global__ __launch_bounds__(256)
void gemm_g2(const ushort* __restrict__ xbf, const float* __restrict__ W1,
             const float* __restrict__ b1, ushort* __restrict__ tbf)
{
  int id = blockIdx.y * 48 + blockIdx.x;
  id = (id & 7) * 48 + (id >> 3);        // XCD swizzle (384 % 8 == 0)
  const int bx = id / 8, by = id % 8;

  const int lane = threadIdx.x & 63, wid = threadIdx.x >> 6;
  const int wr = wid >> 1, wc = wid & 1;
  const int arow = by * 32 + wr * 16 + (lane & 15);
  const int colb = bx * 64 + wc * 32;
  const int kq = (lane >> 4) * 8;

  const ushort* ap = xbf + (size_t)arow * DM + kq;
  const int c0 = colb + (lane & 15), c1 = c0 + 16;
  const float* wrow = W1 + (size_t)kq * FF;

  f32x4 acc0 = (f32x4)(0.0f), acc1 = (f32x4)(0.0f);
  union U { uint4 q; bf16x8 v; };
  U a_c;
  a_c.q = *(const uint4*)ap;
  float b0c[8], b1c[8];
  #pragma unroll
  for (int j = 0; j < 8; ++j) {
    b0c[j] = wrow[(size_t)j * FF + c0];
    b1c[j] = wrow[(size_t)j * FF + c1];
  }

  for (int t = 0; t < 24; ++t) {
    U a_n; float b0n[8], b1n[8];
    const bool more = (t + 1) < 24;
    if (more) {                          // issue next-step loads before MFMA
      a_n.q = *(const uint4*)(ap + (t + 1) * 32);
      const float* w2r = wrow + (size_t)(t + 1) * 32 * FF;
      #pragma unroll
      for (int j = 0; j < 8; ++j) {
        b0n[j] = w2r[(size_t)j * FF + c0];
        b1n[j] = w2r[(size_t)j * FF + c1];
      }
    }
    union V { unsigned u[4]; bf16x8 v; } bfr0, bfr1;
    #pragma unroll
    for (int j = 0; j < 4; ++j) {
      bfr0.u[j] = pk2(b0c[2*j], b0c[2*j+1]);
      bfr1.u[j] = pk2(b1c[2*j], b1c[2*j+1]);
    }
    acc0 = __builtin_amdgcn_mfma_f32_16x16x32_bf16(a_c.v, bfr0.v, acc0, 0, 0, 0);
    acc1 = __builtin_amdgcn_mfma_f32_16x16x32_bf16(a_c.v, bfr1.v, acc1, 0, 0, 0);
    if (more) {
      a_c = a_n;
      #pragma unroll
      for (int j = 0; j < 8; ++j) { b0c[j] = b0n[j]; b1c[j] = b1n[j]; }
    }
  }

  const int crow = by * 32 + wr * 16 + (lane >> 4) * 4;
  #pragma unroll
  for (int nf = 0; nf < 2; ++nf) {
    const int c = colb + nf * 16 + (lane & 15);
    const f32x4 a = nf ? acc1 : acc0;
    #pragma unroll
    for (int r = 0; r < 4; ++r) {
      float v = a[r] + b1[c];
      v = 0.5f * v * (1.0f + erff(v * 0.70710678118654752f));
      tbf[(size_t)(crow + r) * FF + c] = (ushort)bf16rne(v);
    }
  }
}

// ---------------------------------------------------------------------------
// K4 gemm_g3: split-16 (was split-8): A = tbf bf16; B direct from f32 W2
// [FF][DM]. Grid (12,8,16), 6 K-steps per block -- half the r12 chain.
// Epi: f32 partial -> P3[z].
// ---------------------------------------------------------------------------
__global__ __launch_bounds__(256)
void gemm_g3(const ushort* __restrict__ tbf, const float* __restrict__ W2,
             float* __restrict__ P3)
{
  int id = blockIdx.y * 12 + blockIdx.x;
  id = (id & 7) * 12 + (id >> 3);        // XCD swizzle (96 % 8 == 0)
  const int bx = id / 8, by = id % 8;

  const int lane = threadIdx.x & 63, wid = threadIdx.x >> 6;
  const int wr = wid >> 1, wc = wid & 1;
  const int arow = by * 32 + wr * 16 + (lane & 15);
  const int colb = bx * 64 + wc * 32;
  const int kq = (lane >> 4) * 8;
  const int kb = blockIdx.z * 192;       // 6 K-steps per slice

  const ushort* ap = tbf + (size_t)arow * FF + kb + kq;
  const int c0 = colb + (lane & 15), c1 = c0 + 16;
  const float* wrow = W2 + (size_t)(kb + kq) * DM;

  f32x4 acc0 = (f32x4)(0.0f), acc1 = (f32x4)(0.0f);
  union U { uint4 q; bf16x8 v; };
  U a_c;
  a_c.q = *(const uint4*)ap;
  float b0c[8], b1c[8];
  #pragma unroll
  for (int j = 0; j < 8; ++j) {
    b0c[j] = wrow[(size_t)j * DM + c0];
    b1c[j] = wrow[(size_t)j * DM + c1];
  }

  for (int t = 0; t < 6; ++t) {
    U a_n; float b0n[8], b1n[8];
    const bool more = (t + 1) < 6;
    if (more) {                          // issue next-step loads before MFMA
      a_n.q = *(const uint4*)(ap + (t + 1) * 32);
      const float* w2r = wrow + (size_t)(t + 1) * 32 * DM;
      #pragma unroll
      for (int j = 0; j < 8; ++j) {
        b0n[j] = w2r[(size_t)j * DM + c0];
        b1n[j] = w2r[(size_t)j * DM + c1];
      }
    }
    union V { unsigned u[4]; bf16x8 v; } bfr0, bfr1;
    #pragma unroll
    for (int j = 0; j < 4; ++j) {
      bfr0.u[j] = pk2(b0c[2*j], b0c[2*j+1]);
      bfr1.u[j] = pk2(b1c[2*j], b1c[2*j+1]);
    }
    acc0 = __builtin_amdgcn_mfma_f32_16x16x32_bf16(a_c.v, bfr0.v, acc0, 0, 0, 0);
    acc1 = __builtin_amdgcn_mfma_f32_16x16x32_bf16(a_c.v, bfr1.v, acc1, 0, 0, 0);
    if (more) {
      a_c = a_n;
      #pragma unroll
      for (int j = 0; j < 8; ++j) { b0c[j] = b0n[j]; b1c[j] = b1n[j]; }
    }
  }

  const int crow = by * 32 + wr * 16 + (lane >> 4) * 4;
  float* dst = P3 + (size_t)blockIdx.z * BATCH * DM;
  #pragma unroll
  for (int nf = 0; nf < 2; ++nf) {
    const int c = colb + nf * 16 + (lane & 15);
    const f32x4 a = nf ? acc1 : acc0;
    #pragma unroll
    for (int r = 0; r < 4; ++r)
      dst[(size_t)(crow + r) * DM + c] = a[r];
  }
}

// ---------------------------------------------------------------------------
// K5 ln_final: y = xf + sum_{z<16} P3[z] + b2, LayerNorm -> out. 1 block/row.
// ---------------------------------------------------------------------------
__global__ __launch_bounds__(256)
void ln_final(const float* __restrict__ P3, const float* __restrict__ xf,
              const float* __restrict__ b2, const float* __restrict__ g,
              const float* __restrict__ be, float* __restrict__ out)
{
  const int row = blockIdx.x, tid = threadIdx.x;
  const int lane = tid & 63, wave = tid >> 6;

  float v[3];
  #pragma unroll
  for (int i = 0; i < 3; ++i) {
    const int c = tid + i * 256;
    float s = xf[(size_t)row * DM + c] + b2[c];
    #pragma unroll
    for (int z = 0; z < 16; ++z) s += P3[((size_t)z * BATCH + row) * DM + c];
    v[i] = s;
  }

  __shared__ float red[4];
  float s = v[0] + v[1] + v[2];
  #pragma unroll
  for (int o = 32; o > 0; o >>= 1) s += __shfl_down(s, o);
  if (lane == 0) red[wave] = s;
  __syncthreads();
  const float mu = (red[0] + red[1] + red[2] + red[3]) * (1.0f / 768.0f);
  __syncthreads();
  const float d0 = v[0] - mu, d1 = v[1] - mu, d2 = v[2] - mu;
  float q = d0*d0 + d1*d1 + d2*d2;
  #pragma unroll
  for (int o = 32; o > 0; o >>= 1) q += __shfl_down(q, o);
  if (lane == 0) red[wave] = q;
  __syncthreads();
  const float var = (red[0] + red[1] + red[2] + red[3]) * (1.0f / 768.0f);
  const float inv = rsqrtf(var + 1e-12f);

  float* o = out + (size_t)row * DM;
  o[tid      ] = d0 * inv * g[tid      ] + be[tid      ];
  o[tid + 256] = d1 * inv * g[tid + 256] + be[tid + 256];
  o[tid + 512] = d2 * inv * g[tid + 512] + be[tid + 512];
}

// ---------------------------------------------------------------------------
// 5 kernels (r12 structure; G1 split 4->8, G3 split 8->16 to halve serial
// K-chains): G1 -> fixup -> G2 -> G3 -> LN. ws ~21.5 MB.
// ---------------------------------------------------------------------------
extern "C" void kernel_launch(void* const* d_in, const int* in_sizes, int n_in,
                              void* d_out, int out_size, void* d_ws, size_t ws_size,
                              hipStream_t stream)
{
  const float* im  = (const float*)d_in[0];
  const float* Wv2 = (const float*)d_in[12];
  const float* bv2 = (const float*)d_in[13];
  const float* W1  = (const float*)d_in[14];
  const float* b1  = (const float*)d_in[15];
  const float* W2  = (const float*)d_in[16];
  const float* b2  = (const float*)d_in[17];
  const float* g   = (const float*)d_in[18];
  const float* be  = (const float*)d_in[19];
  float* out = (float*)d_out;

  char* w = (char*)d_ws;
  ushort* xbf = (ushort*)(w);                // 256*768*2    = 393216
  ushort* tbf = (ushort*)(w + 393216);       // 256*3072*2   = 1572864
  float*  xf  = (float*) (w + 1966080);      // 256*768*4    = 786432
  float*  P1  = (float*) (w + 2752512);      // 8*256*768*4  = 6291456
  float*  P3  = (float*) (w + 9043968);      // 16*256*768*4 = 12582912 -> 21.6MB

  // K1: P1[z] = im @ Wv2 slices (direct f32 B, split-8, 4-step chains)
  gemm_g1<<<dim3(12, 8, 8), 256, 0, stream>>>(Wv2, im, P1);
  // K2: x = sum P1 + bv2 -> xf, xbf
  fixup_x<<<192, 256, 0, stream>>>(P1, bv2, xf, xbf);
  // K3: tbf = bf16(gelu(x @ W1 + b1))   (direct f32 B)
  gemm_g2<<<dim3(48, 8, 1), 256, 0, stream>>>(xbf, W1, b1, tbf);
  // K4: P3[z] = (t @ W2) K-slices       (direct f32 B, split-16, 6-step chains)
  gemm_g3<<<dim3(12, 8, 16), 256, 0, stream>>>(tbf, W2, P3);
  // K5: LN(xf + sum P3 + b2) -> out
  ln_final<<<BATCH, 256, 0, stream>>>(P3, xf, b2, g, be, out);
}